// Round 1
// baseline (10057.555 us; speedup 1.0000x reference)
//
#include <hip/hip_runtime.h>
#include <cstdint>
#include <cstddef>

#define TT 2048
#define DD 128
#define HH 256
#define G4 1024

typedef _Float16 half4_t __attribute__((ext_vector_type(4)));
typedef _Float16 half8_t __attribute__((ext_vector_type(8)));
typedef float floatx4 __attribute__((ext_vector_type(4)));

union H4U64 { uint64_t u; half4_t h; };
union H8U64x2 { uint64_t u[2]; half8_t h; };

__device__ __forceinline__ float sigm(float x) { return 1.f / (1.f + __expf(-x)); }
__device__ __forceinline__ float tanh_f(float x) { return 1.f - 2.f / (1.f + __expf(2.f * x)); }

__device__ __forceinline__ half8_t cvt8(float4 a, float4 b) {
  half8_t v;
  v[0] = (_Float16)a.x; v[1] = (_Float16)a.y; v[2] = (_Float16)a.z; v[3] = (_Float16)a.w;
  v[4] = (_Float16)b.x; v[5] = (_Float16)b.y; v[6] = (_Float16)b.z; v[7] = (_Float16)b.w;
  return v;
}

// ---------------- prep: RT[dir][n][k<256] = R[k][n] fp16 ; KT[dir][n][k<128] = K[k][n] fp16 ----
__global__ void prep_kernel(const float* __restrict__ rf, const float* __restrict__ rb,
                            const float* __restrict__ kf, const float* __restrict__ kb,
                            _Float16* __restrict__ RT, _Float16* __restrict__ KT) {
  int idx = blockIdx.x * 256 + threadIdx.x;     // 0 .. 786431
  if (idx < 2 * G4 * HH) {
    int dir = idx >> 18, k = (idx >> 10) & 255, n = idx & 1023;
    const float* src = dir ? rb : rf;
    RT[((size_t)(dir * G4 + n)) * HH + k] = (_Float16)src[(size_t)k * G4 + n];
  } else {
    int i2 = idx - 2 * G4 * HH;
    int dir = i2 >> 17, k = (i2 >> 10) & 127, n = i2 & 1023;
    const float* src = dir ? kb : kf;
    KT[((size_t)(dir * G4 + n)) * DD + k] = (_Float16)src[(size_t)k * G4 + n];
  }
}

// ---------------- recurrence ----------------
// 32 blocks = 4 splits x (2 dirs x 4 batch-groups g), 256 thr (4 waves).
// Round-7 protocol: SENTINEL-IN-DATA. hseq is pre-filled with 0xFF (half 0xFFFF = -NaN,
// impossible for tanh-bounded h). Producer publishes h_s as ONE relaxed agent-scope u64
// store per thread directly into hseq (single-copy atomic) — no ring, no flags, no
// vmcnt drain. Consumer issues the 16x8B gather into hseq[t_prev] immediately, overlaps
// the xproj MFMAs with the flight, then polls: word ready iff != 0xFFFF..F; only
// sentinel words are re-loaded. Per-step cross-CU cost: ~1 store-propagate + ~1 poll
// discovery (was: store-drain RT + flag RT + gather RT).

#define SENT 0xFFFFFFFFFFFFFFFFull

__global__ __launch_bounds__(256, 1) void lstm_rec_kernel(
    const float* __restrict__ x,
    const float* __restrict__ bias_f, const float* __restrict__ bias_b,
    const _Float16* __restrict__ RT, const _Float16* __restrict__ KT,
    _Float16* __restrict__ hseq) {
  const int bid = blockIdx.x;            // split*8 + g   (g = dir*4 + bg)
  const int split = bid >> 3;
  const int g = bid & 7;
  const int dir = g >> 2;
  const int bg = g & 3;
  const int tid = threadIdx.x;
  const int w = tid >> 6, lane = tid & 63;
  const int lo16 = lane & 15, q = lane >> 4;

  __shared__ _Float16 tile[2][64][20];   // [parity][h_local][batch padded 16->20]

  const float* __restrict__ bias = dir ? bias_b : bias_f;

  // persistent B-fragments (k-contiguous in RT/KT rows) — verified layout (rounds 4/5)
  half8_t bR[4][8], bK[4][4];
  float bgate[4];
#pragma unroll
  for (int gate = 0; gate < 4; ++gate) {
    const int col = gate * 256 + split * 64 + w * 16 + lo16;
    const _Float16* bp = RT + (size_t)(dir * G4 + col) * HH + q * 8;
#pragma unroll
    for (int kk = 0; kk < 8; ++kk) bR[gate][kk] = *reinterpret_cast<const half8_t*>(bp + kk * 32);
    const _Float16* kp = KT + (size_t)(dir * G4 + col) * DD + q * 8;
#pragma unroll
    for (int kx = 0; kx < 4; ++kx) bK[gate][kx] = *reinterpret_cast<const half8_t*>(kp + kx * 32);
    bgate[gate] = bias[col];
  }

  // x row for this lane's batch (A-operand row m = lo16)
  const float* __restrict__ xrow = x + ((size_t)(bg * 16 + lo16) * TT) * DD;

  // transpose/publish role of this thread
  const int kgl  = tid >> 5;            // 0..7 local k-group (8 h each)
  const int tb   = (tid >> 1) & 15;     // batch
  const int part = tid & 1;             // low/high 4 halfs
  const int hofsq = split * 16 + kgl * 2 + part;   // u64 offset within the 256-h row

  uint64_t* __restrict__ hq = (uint64_t*)hseq;     // u64 view: [g][t][b16][h/4]
  const size_t gbase = (size_t)g * TT;             // in t units; *1024 u64 per t

  float c[4] = {0.f, 0.f, 0.f, 0.f};

  // prefetch x fragments for s=0
  int tx = dir ? TT - 1 : 0;
  float4 xr[8];
  {
    const float* xp = xrow + (size_t)tx * DD + q * 8;
#pragma unroll
    for (int kx = 0; kx < 4; ++kx) {
      xr[2 * kx]     = *reinterpret_cast<const float4*>(xp + kx * 32);
      xr[2 * kx + 1] = *reinterpret_cast<const float4*>(xp + kx * 32 + 4);
    }
  }
  half8_t ax[4];
#pragma unroll
  for (int kx = 0; kx < 4; ++kx) ax[kx] = cvt8(xr[2 * kx], xr[2 * kx + 1]);

  for (int s = 0; s < TT; ++s) {
    tx = dir ? (TT - 1 - s) : s;

    // issue the gather FIRST (it is the critical path): 16 x 8B from hseq[t of s-1]
    uint64_t g0[8], g1[8];
    const uint64_t* gp = hq;
    if (s > 0) {
      const int txp = dir ? (TT - s) : (s - 1);
      gp = hq + (gbase + txp) * 1024 + (size_t)(lo16 * 64 + q * 2);
#pragma unroll
      for (int kk = 0; kk < 8; ++kk) {
        g0[kk] = __hip_atomic_load(gp + kk * 8,     __ATOMIC_RELAXED, __HIP_MEMORY_SCOPE_AGENT);
        g1[kk] = __hip_atomic_load(gp + kk * 8 + 1, __ATOMIC_RELAXED, __HIP_MEMORY_SCOPE_AGENT);
      }
    }

    // prefetch next step's x (drains in background)
    {
      const int sn = (s + 1 < TT) ? s + 1 : s;
      const int txn = dir ? (TT - 1 - sn) : sn;
      const float* xp = xrow + (size_t)txn * DD + q * 8;
#pragma unroll
      for (int kx = 0; kx < 4; ++kx) {
        xr[2 * kx]     = *reinterpret_cast<const float4*>(xp + kx * 32);
        xr[2 * kx + 1] = *reinterpret_cast<const float4*>(xp + kx * 32 + 4);
      }
    }

    floatx4 acc[4];
#pragma unroll
    for (int gate = 0; gate < 4; ++gate) acc[gate] = floatx4{0.f, 0.f, 0.f, 0.f};

    // xproj MFMAs execute while the gather is in flight
#pragma unroll
    for (int kx = 0; kx < 4; ++kx)
#pragma unroll
      for (int gate = 0; gate < 4; ++gate)
        acc[gate] = __builtin_amdgcn_mfma_f32_16x16x32_f16(ax[kx], bK[gate][kx], acc[gate], 0, 0, 0);

    if (s > 0) {
      // data-as-flag poll: a word is ready iff != SENT (producer u64 store is
      // single-copy atomic; real h halfs are tanh outputs, never 0xFFFF NaN)
      while (true) {
        bool ok = true;
#pragma unroll
        for (int kk = 0; kk < 8; ++kk) ok = ok & (g0[kk] != SENT) & (g1[kk] != SENT);
        if (__all(ok)) break;
#pragma unroll
        for (int kk = 0; kk < 8; ++kk) {
          if (g0[kk] == SENT)
            g0[kk] = __hip_atomic_load(gp + kk * 8,     __ATOMIC_RELAXED, __HIP_MEMORY_SCOPE_AGENT);
          if (g1[kk] == SENT)
            g1[kk] = __hip_atomic_load(gp + kk * 8 + 1, __ATOMIC_RELAXED, __HIP_MEMORY_SCOPE_AGENT);
        }
      }
#pragma unroll
      for (int kk = 0; kk < 8; ++kk) {
        H8U64x2 u;
        u.u[0] = g0[kk];
        u.u[1] = g1[kk];
#pragma unroll
        for (int gate = 0; gate < 4; ++gate)
          acc[gate] = __builtin_amdgcn_mfma_f32_16x16x32_f16(u.h, bR[gate][kk], acc[gate], 0, 0, 0);
      }
    }

    // gates: lane holds (batch=q*4+r, h_idx=split*64+w*16+lo16); order i,f,g,o
    const int par = s & 1;
    {
      half4_t hv4;
#pragma unroll
      for (int r = 0; r < 4; ++r) {
        const float zi = acc[0][r] + bgate[0];
        const float zf = acc[1][r] + bgate[1];
        const float zg = acc[2][r] + bgate[2];
        const float zo = acc[3][r] + bgate[3];
        c[r] = sigm(zf) * c[r] + sigm(zi) * tanh_f(zg);
        hv4[r] = (_Float16)(sigm(zo) * tanh_f(c[r]));
      }
      *reinterpret_cast<half4_t*>(&tile[par][w * 16 + lo16][q * 4]) = hv4;
    }
    __syncthreads();                     // tile[par] visible block-wide (only barrier per step)

    // transpose-publish: ONE u64 agent store straight into hseq (data carries readiness)
    {
      H4U64 val;
#pragma unroll
      for (int j = 0; j < 4; ++j) val.h[j] = tile[par][kgl * 8 + part * 4 + j][tb];
      __hip_atomic_store(hq + (gbase + tx) * 1024 + (size_t)(tb * 64 + hofsq), val.u,
                         __ATOMIC_RELAXED, __HIP_MEMORY_SCOPE_AGENT);
    }

    // convert prefetched x for next step
#pragma unroll
    for (int kx = 0; kx < 4; ++kx) ax[kx] = cvt8(xr[2 * kx], xr[2 * kx + 1]);
  }
}

// ---------------- attention: one block per batch; hseq layout [g][t][b16][h] ----------------

__global__ __launch_bounds__(256) void attn_kernel(const _Float16* __restrict__ h_ex,
                                                   const float* __restrict__ att_w,
                                                   float* __restrict__ out) {
  const int b = blockIdx.x;
  const int bg = b >> 4, b16 = b & 15;
  const int tid = threadIdx.x;
  const int w = tid >> 6, lane = tid & 63;
  __shared__ float sc[TT];
  __shared__ float red[8];
  const size_t ST = 16 * HH;
  const _Float16* __restrict__ hf = h_ex + (size_t)bg * TT * ST + b16 * HH;
  const _Float16* __restrict__ hb = h_ex + (size_t)(4 + bg) * TT * ST + b16 * HH;

  const int h0 = lane * 4;
  const float aw0 = att_w[h0], aw1 = att_w[h0 + 1], aw2 = att_w[h0 + 2], aw3 = att_w[h0 + 3];

  for (int t = w; t < TT; t += 4) {
    half4_t f4 = *reinterpret_cast<const half4_t*>(hf + (size_t)t * ST + h0);
    half4_t b4 = *reinterpret_cast<const half4_t*>(hb + (size_t)t * ST + h0);
    float s = aw0 * tanh_f((float)f4[0] + (float)b4[0])
            + aw1 * tanh_f((float)f4[1] + (float)b4[1])
            + aw2 * tanh_f((float)f4[2] + (float)b4[2])
            + aw3 * tanh_f((float)f4[3] + (float)b4[3]);
#pragma unroll
    for (int off = 32; off >= 1; off >>= 1) s += __shfl_xor(s, off);
    if (lane == 0) sc[t] = s;
  }
  __syncthreads();

  float m = -1e30f;
  for (int i = tid; i < TT; i += 256) m = fmaxf(m, sc[i]);
#pragma unroll
  for (int off = 32; off >= 1; off >>= 1) m = fmaxf(m, __shfl_xor(m, off));
  if (lane == 0) red[w] = m;
  __syncthreads();
  m = fmaxf(fmaxf(red[0], red[1]), fmaxf(red[2], red[3]));

  float ssum = 0.f;
  for (int i = tid; i < TT; i += 256) {
    float e = __expf(sc[i] - m);
    sc[i] = e;
    ssum += e;
  }
#pragma unroll
  for (int off = 32; off >= 1; off >>= 1) ssum += __shfl_xor(ssum, off);
  if (lane == 0) red[4 + w] = ssum;
  __syncthreads();
  const float inv = 1.f / (red[4] + red[5] + red[6] + red[7]);

  float r = 0.f;
  const _Float16* pf = hf + tid;
  const _Float16* pb = hb + tid;
  for (int t = 0; t < TT; ++t)
    r += sc[t] * ((float)pf[(size_t)t * ST] + (float)pb[(size_t)t * ST]);
  out[b * HH + tid] = tanh_f(r * inv);
}

// ---------------- launch ----------------

extern "C" void kernel_launch(void* const* d_in, const int* in_sizes, int n_in,
                              void* d_out, int out_size, void* d_ws, size_t ws_size,
                              hipStream_t stream) {
  const float* x     = (const float*)d_in[0];
  const float* k_fwd = (const float*)d_in[1];
  const float* r_fwd = (const float*)d_in[2];
  const float* b_fwd = (const float*)d_in[3];
  const float* k_bwd = (const float*)d_in[4];
  const float* r_bwd = (const float*)d_in[5];
  const float* b_bwd = (const float*)d_in[6];
  const float* att_w = (const float*)d_in[7];
  float* out = (float*)d_out;

  // ws: RT 1 MB + KT 0.5 MB + hseq 128 MB  (~129.5 MB)
  const size_t RT_bytes   = (size_t)2 * G4 * HH * sizeof(_Float16);
  const size_t KT_bytes   = (size_t)2 * G4 * DD * sizeof(_Float16);
  const size_t hseq_bytes = (size_t)8 * TT * 16 * HH * sizeof(_Float16);
  char* ws = (char*)d_ws;
  _Float16* RT   = (_Float16*)ws;
  _Float16* KT   = (_Float16*)(ws + RT_bytes);
  _Float16* hseq = (_Float16*)(ws + RT_bytes + KT_bytes);

  // sentinel-fill hseq: half 0xFFFF = -NaN, never produced by tanh-bounded h
  hipMemsetAsync(hseq, 0xFF, hseq_bytes, stream);
  hipLaunchKernelGGL(prep_kernel, dim3(3072), dim3(256), 0, stream,
                     r_fwd, r_bwd, k_fwd, k_bwd, RT, KT);
  hipLaunchKernelGGL(lstm_rec_kernel, dim3(32), dim3(256), 0, stream,
                     x, b_fwd, b_bwd, RT, KT, hseq);
  hipLaunchKernelGGL(attn_kernel, dim3(64), dim3(256), 0, stream, hseq, att_w, out);
}

// Round 2
// 7312.241 us; speedup vs baseline: 1.3754x; 1.3754x over previous
//
#include <hip/hip_runtime.h>
#include <cstdint>
#include <cstddef>

#define TT 2048
#define DD 128
#define HH 256
#define G4 1024

typedef _Float16 half4_t __attribute__((ext_vector_type(4)));
typedef _Float16 half8_t __attribute__((ext_vector_type(8)));
typedef float floatx4 __attribute__((ext_vector_type(4)));

union H4U64 { uint64_t u; half4_t h; };
union H8U64x2 { uint64_t u[2]; half8_t h; };

__device__ __forceinline__ float sigm(float x) { return 1.f / (1.f + __expf(-x)); }
__device__ __forceinline__ float tanh_f(float x) { return 1.f - 2.f / (1.f + __expf(2.f * x)); }

__device__ __forceinline__ half8_t cvt8(float4 a, float4 b) {
  half8_t v;
  v[0] = (_Float16)a.x; v[1] = (_Float16)a.y; v[2] = (_Float16)a.z; v[3] = (_Float16)a.w;
  v[4] = (_Float16)b.x; v[5] = (_Float16)b.y; v[6] = (_Float16)b.z; v[7] = (_Float16)b.w;
  return v;
}

// ---------------- prep: RT[dir][n][k<256] = R[k][n] fp16 ; KT[dir][n][k<128] = K[k][n] fp16 ----
__global__ void prep_kernel(const float* __restrict__ rf, const float* __restrict__ rb,
                            const float* __restrict__ kf, const float* __restrict__ kb,
                            _Float16* __restrict__ RT, _Float16* __restrict__ KT) {
  int idx = blockIdx.x * 256 + threadIdx.x;     // 0 .. 786431
  if (idx < 2 * G4 * HH) {
    int dir = idx >> 18, k = (idx >> 10) & 255, n = idx & 1023;
    const float* src = dir ? rb : rf;
    RT[((size_t)(dir * G4 + n)) * HH + k] = (_Float16)src[(size_t)k * G4 + n];
  } else {
    int i2 = idx - 2 * G4 * HH;
    int dir = i2 >> 17, k = (i2 >> 10) & 127, n = i2 & 1023;
    const float* src = dir ? kb : kf;
    KT[((size_t)(dir * G4 + n)) * DD + k] = (_Float16)src[(size_t)k * G4 + n];
  }
}

// ---------------- recurrence ----------------
// 32 blocks = 4 splits x (2 dirs x 4 batch-groups g), 256 thr (4 waves).
// Round-8 protocol: SENTINEL-IN-RING, no flags.
//   Ring = 4 slots x 8 KB per group, MALL-resident (round-7 regressed because the
//   gather targeted the 128-MB hseq whose sentinel lines evicted to HBM: FETCH +45 MB).
//   Producer: LDS transpose -> ring u64 relaxed agent store (the data IS the signal)
//   -> hseq plain store. The per-step __syncthreads vmcnt(0) drain orders everything.
//   Consumer: gather slot (s-1)&3 speculatively at step start, overlap xproj MFMAs,
//   poll != SENT re-loading only sentinel words.
//   Slot recycle: each thread resets ITS OWN u64 in slot (s+2)&3 right after gather
//   success. Safety: gather success at s  =>  partners published h_{s-1}  =>  consumed
//   h_{s-2} (slot (s+2)&3's content), so nothing live is destroyed; the barrier drain
//   before publish + per-location coherence (same thread, same address) kill ABA.

#define SENT 0xFFFFFFFFFFFFFFFFull

__global__ __launch_bounds__(256, 1) void lstm_rec_kernel(
    const float* __restrict__ x,
    const float* __restrict__ bias_f, const float* __restrict__ bias_b,
    const _Float16* __restrict__ RT, const _Float16* __restrict__ KT,
    uint64_t* __restrict__ ring, _Float16* __restrict__ hseq) {
  const int bid = blockIdx.x;            // split*8 + g   (g = dir*4 + bg)
  const int split = bid >> 3;
  const int g = bid & 7;
  const int dir = g >> 2;
  const int bg = g & 3;
  const int tid = threadIdx.x;
  const int w = tid >> 6, lane = tid & 63;
  const int lo16 = lane & 15, q = lane >> 4;

  __shared__ _Float16 tile[2][64][20];   // [parity][h_local][batch padded 16->20]

  const float* __restrict__ bias = dir ? bias_b : bias_f;

  // persistent B-fragments (k-contiguous in RT/KT rows) — verified layout (rounds 4/5)
  half8_t bR[4][8], bK[4][4];
  float bgate[4];
#pragma unroll
  for (int gate = 0; gate < 4; ++gate) {
    const int col = gate * 256 + split * 64 + w * 16 + lo16;
    const _Float16* bp = RT + (size_t)(dir * G4 + col) * HH + q * 8;
#pragma unroll
    for (int kk = 0; kk < 8; ++kk) bR[gate][kk] = *reinterpret_cast<const half8_t*>(bp + kk * 32);
    const _Float16* kp = KT + (size_t)(dir * G4 + col) * DD + q * 8;
#pragma unroll
    for (int kx = 0; kx < 4; ++kx) bK[gate][kx] = *reinterpret_cast<const half8_t*>(kp + kx * 32);
    bgate[gate] = bias[col];
  }

  // x row for this lane's batch (A-operand row m = lo16)
  const float* __restrict__ xrow = x + ((size_t)(bg * 16 + lo16) * TT) * DD;

  // transpose/publish role of this thread
  const int kgl  = tid >> 5;            // 0..7 local k-group (8 h each)
  const int tb   = (tid >> 1) & 15;     // batch
  const int part = tid & 1;             // low/high 4 halfs
  const int kg_global = split * 8 + kgl;
  const int hofs = split * 64 + kgl * 8 + part * 4;
  const int myofs = (kg_global * 16 + tb) * 2 + part;   // this thread's u64 position in a slot

  float c[4] = {0.f, 0.f, 0.f, 0.f};

  // prefetch x fragments for s=0
  int tx = dir ? TT - 1 : 0;
  float4 xr[8];
  {
    const float* xp = xrow + (size_t)tx * DD + q * 8;
#pragma unroll
    for (int kx = 0; kx < 4; ++kx) {
      xr[2 * kx]     = *reinterpret_cast<const float4*>(xp + kx * 32);
      xr[2 * kx + 1] = *reinterpret_cast<const float4*>(xp + kx * 32 + 4);
    }
  }
  half8_t ax[4];
#pragma unroll
  for (int kx = 0; kx < 4; ++kx) ax[kx] = cvt8(xr[2 * kx], xr[2 * kx + 1]);

  for (int s = 0; s < TT; ++s) {
    tx = dir ? (TT - 1 - s) : s;

    // issue the ring gather FIRST (it is the critical path): 16 x 8B from slot (s-1)&3
    uint64_t g0[8], g1[8];
    const uint64_t* gp = ring;
    if (s > 0) {
      gp = ring + ((size_t)((((s - 1) & 3) * 8 + g))) * 1024 + (size_t)((q * 16 + lo16) * 2);
      // note: gather address pattern identical to round-6: u64 idx = (kk*4+q)*32 + lo16*2
#pragma unroll
      for (int kk = 0; kk < 8; ++kk) {
        g0[kk] = __hip_atomic_load(gp + (size_t)kk * 128,     __ATOMIC_RELAXED, __HIP_MEMORY_SCOPE_AGENT);
        g1[kk] = __hip_atomic_load(gp + (size_t)kk * 128 + 1, __ATOMIC_RELAXED, __HIP_MEMORY_SCOPE_AGENT);
      }
    }

    // prefetch next step's x (drains in background)
    {
      const int sn = (s + 1 < TT) ? s + 1 : s;
      const int txn = dir ? (TT - 1 - sn) : sn;
      const float* xp = xrow + (size_t)txn * DD + q * 8;
#pragma unroll
      for (int kx = 0; kx < 4; ++kx) {
        xr[2 * kx]     = *reinterpret_cast<const float4*>(xp + kx * 32);
        xr[2 * kx + 1] = *reinterpret_cast<const float4*>(xp + kx * 32 + 4);
      }
    }

    floatx4 acc[4];
#pragma unroll
    for (int gate = 0; gate < 4; ++gate) acc[gate] = floatx4{0.f, 0.f, 0.f, 0.f};

    // xproj MFMAs execute while the gather is in flight
#pragma unroll
    for (int kx = 0; kx < 4; ++kx)
#pragma unroll
      for (int gate = 0; gate < 4; ++gate)
        acc[gate] = __builtin_amdgcn_mfma_f32_16x16x32_f16(ax[kx], bK[gate][kx], acc[gate], 0, 0, 0);

    if (s > 0) {
      // data-as-flag poll: a word is ready iff != SENT (producer u64 store is
      // single-copy atomic; real h halfs are tanh outputs, never 0xFFFF NaN)
      while (true) {
        bool ok = true;
#pragma unroll
        for (int kk = 0; kk < 8; ++kk) ok = ok & (g0[kk] != SENT) & (g1[kk] != SENT);
        if (__all(ok)) break;
#pragma unroll
        for (int kk = 0; kk < 8; ++kk) {
          if (g0[kk] == SENT)
            g0[kk] = __hip_atomic_load(gp + (size_t)kk * 128,     __ATOMIC_RELAXED, __HIP_MEMORY_SCOPE_AGENT);
          if (g1[kk] == SENT)
            g1[kk] = __hip_atomic_load(gp + (size_t)kk * 128 + 1, __ATOMIC_RELAXED, __HIP_MEMORY_SCOPE_AGENT);
        }
      }

      // recycle: reset my own u64 in slot (s+2)&3 (holds h_{s-2}, provably consumed by
      // all partners once this step's gather succeeded). Fire-and-forget; the barrier's
      // vmcnt(0) drain before this step's publish orders it ahead of the slot's rewrite.
      __hip_atomic_store(ring + ((size_t)((((s + 2) & 3) * 8 + g))) * 1024 + myofs, SENT,
                         __ATOMIC_RELAXED, __HIP_MEMORY_SCOPE_AGENT);

#pragma unroll
      for (int kk = 0; kk < 8; ++kk) {
        H8U64x2 u;
        u.u[0] = g0[kk];
        u.u[1] = g1[kk];
#pragma unroll
        for (int gate = 0; gate < 4; ++gate)
          acc[gate] = __builtin_amdgcn_mfma_f32_16x16x32_f16(u.h, bR[gate][kk], acc[gate], 0, 0, 0);
      }
    }

    // gates: lane holds (batch=q*4+r, h_idx=split*64+w*16+lo16); order i,f,g,o
    const int par = s & 1;
    {
      half4_t hv4;
#pragma unroll
      for (int r = 0; r < 4; ++r) {
        const float zi = acc[0][r] + bgate[0];
        const float zf = acc[1][r] + bgate[1];
        const float zg = acc[2][r] + bgate[2];
        const float zo = acc[3][r] + bgate[3];
        c[r] = sigm(zf) * c[r] + sigm(zi) * tanh_f(zg);
        hv4[r] = (_Float16)(sigm(zo) * tanh_f(c[r]));
      }
      *reinterpret_cast<half4_t*>(&tile[par][w * 16 + lo16][q * 4]) = hv4;
    }
    __syncthreads();   // tile[par] visible block-wide; also drains vmcnt(0) (reset ordering)

    // transpose-publish: ONE u64 agent store into the ring (data carries readiness),
    // then the hseq HBM store (off critical path, drains under next step's compute)
    {
      H4U64 val;
#pragma unroll
      for (int j = 0; j < 4; ++j) val.h[j] = tile[par][kgl * 8 + part * 4 + j][tb];
      asm volatile("s_waitcnt vmcnt(0)" ::: "memory");   // belt-and-braces reset ordering
      __hip_atomic_store(ring + ((size_t)((s & 3) * 8 + g)) * 1024 + myofs, val.u,
                         __ATOMIC_RELAXED, __HIP_MEMORY_SCOPE_AGENT);
      *reinterpret_cast<uint64_t*>(hseq + ((size_t)g * TT + tx) * (16 * HH) + (size_t)tb * HH + hofs) = val.u;
    }

    // convert prefetched x for next step
#pragma unroll
    for (int kx = 0; kx < 4; ++kx) ax[kx] = cvt8(xr[2 * kx], xr[2 * kx + 1]);
  }
}

// ---------------- attention: one block per batch; hseq layout [g][t][b16][h] ----------------

__global__ __launch_bounds__(256) void attn_kernel(const _Float16* __restrict__ h_ex,
                                                   const float* __restrict__ att_w,
                                                   float* __restrict__ out) {
  const int b = blockIdx.x;
  const int bg = b >> 4, b16 = b & 15;
  const int tid = threadIdx.x;
  const int w = tid >> 6, lane = tid & 63;
  __shared__ float sc[TT];
  __shared__ float red[8];
  const size_t ST = 16 * HH;
  const _Float16* __restrict__ hf = h_ex + (size_t)bg * TT * ST + b16 * HH;
  const _Float16* __restrict__ hb = h_ex + (size_t)(4 + bg) * TT * ST + b16 * HH;

  const int h0 = lane * 4;
  const float aw0 = att_w[h0], aw1 = att_w[h0 + 1], aw2 = att_w[h0 + 2], aw3 = att_w[h0 + 3];

  for (int t = w; t < TT; t += 4) {
    half4_t f4 = *reinterpret_cast<const half4_t*>(hf + (size_t)t * ST + h0);
    half4_t b4 = *reinterpret_cast<const half4_t*>(hb + (size_t)t * ST + h0);
    float s = aw0 * tanh_f((float)f4[0] + (float)b4[0])
            + aw1 * tanh_f((float)f4[1] + (float)b4[1])
            + aw2 * tanh_f((float)f4[2] + (float)b4[2])
            + aw3 * tanh_f((float)f4[3] + (float)b4[3]);
#pragma unroll
    for (int off = 32; off >= 1; off >>= 1) s += __shfl_xor(s, off);
    if (lane == 0) sc[t] = s;
  }
  __syncthreads();

  float m = -1e30f;
  for (int i = tid; i < TT; i += 256) m = fmaxf(m, sc[i]);
#pragma unroll
  for (int off = 32; off >= 1; off >>= 1) m = fmaxf(m, __shfl_xor(m, off));
  if (lane == 0) red[w] = m;
  __syncthreads();
  m = fmaxf(fmaxf(red[0], red[1]), fmaxf(red[2], red[3]));

  float ssum = 0.f;
  for (int i = tid; i < TT; i += 256) {
    float e = __expf(sc[i] - m);
    sc[i] = e;
    ssum += e;
  }
#pragma unroll
  for (int off = 32; off >= 1; off >>= 1) ssum += __shfl_xor(ssum, off);
  if (lane == 0) red[4 + w] = ssum;
  __syncthreads();
  const float inv = 1.f / (red[4] + red[5] + red[6] + red[7]);

  float r = 0.f;
  const _Float16* pf = hf + tid;
  const _Float16* pb = hb + tid;
  for (int t = 0; t < TT; ++t)
    r += sc[t] * ((float)pf[(size_t)t * ST] + (float)pb[(size_t)t * ST]);
  out[b * HH + tid] = tanh_f(r * inv);
}

// ---------------- launch ----------------

extern "C" void kernel_launch(void* const* d_in, const int* in_sizes, int n_in,
                              void* d_out, int out_size, void* d_ws, size_t ws_size,
                              hipStream_t stream) {
  const float* x     = (const float*)d_in[0];
  const float* k_fwd = (const float*)d_in[1];
  const float* r_fwd = (const float*)d_in[2];
  const float* b_fwd = (const float*)d_in[3];
  const float* k_bwd = (const float*)d_in[4];
  const float* r_bwd = (const float*)d_in[5];
  const float* b_bwd = (const float*)d_in[6];
  const float* att_w = (const float*)d_in[7];
  float* out = (float*)d_out;

  // ws: RT 1 MB + KT 0.5 MB + ring 256 KB + hseq 128 MB  (~129.75 MB)
  const size_t RT_bytes   = (size_t)2 * G4 * HH * sizeof(_Float16);
  const size_t KT_bytes   = (size_t)2 * G4 * DD * sizeof(_Float16);
  const size_t ring_bytes = (size_t)4 * 8 * 1024 * sizeof(uint64_t);   // 4 slots x 8 g x 1024 u64
  char* ws = (char*)d_ws;
  _Float16* RT    = (_Float16*)ws;
  _Float16* KT    = (_Float16*)(ws + RT_bytes);
  uint64_t* ring  = (uint64_t*)(ws + RT_bytes + KT_bytes);
  _Float16* hseq  = (_Float16*)(ws + RT_bytes + KT_bytes + ring_bytes);

  // sentinel-fill the ring: half 0xFFFF = -NaN, never produced by tanh-bounded h
  hipMemsetAsync(ring, 0xFF, ring_bytes, stream);
  hipLaunchKernelGGL(prep_kernel, dim3(3072), dim3(256), 0, stream,
                     r_fwd, r_bwd, k_fwd, k_bwd, RT, KT);
  hipLaunchKernelGGL(lstm_rec_kernel, dim3(32), dim3(256), 0, stream,
                     x, b_fwd, b_bwd, RT, KT, ring, hseq);
  hipLaunchKernelGGL(attn_kernel, dim3(64), dim3(256), 0, stream, hseq, att_w, out);
}